// Round 9
// baseline (688.497 us; speedup 1.0000x reference)
//
#include <hip/hip_runtime.h>

#define NNODES 50000
#define NEDGES 1600000
#define FEAT   128
#define EPSV   1e-5f
#define NBUCK  ((NNODES + 511) / 512)   // 98 buckets of 512 nodes

typedef _Float16 h8 __attribute__((ext_vector_type(8)));
typedef _Float16 h4 __attribute__((ext_vector_type(4)));

__device__ __forceinline__ float4 f4fma(float s, float4 w, float4 a) {
  a.x = fmaf(s, w.x, a.x); a.y = fmaf(s, w.y, a.y);
  a.z = fmaf(s, w.z, a.z); a.w = fmaf(s, w.w, a.w);
  return a;
}

// ---------------- sum of all x (for mean) ----------------
__global__ __launch_bounds__(256) void sum_kernel(const float* __restrict__ x,
                                                  float* __restrict__ out, int n4) {
  const float4* x4 = (const float4*)x;
  float s = 0.f;
  for (int i = blockIdx.x * blockDim.x + threadIdx.x; i < n4; i += gridDim.x * blockDim.x) {
    float4 v = x4[i];
    s += v.x + v.y + v.z + v.w;
  }
  for (int off = 32; off > 0; off >>= 1) s += __shfl_down(s, off);
  __shared__ float ls[4];
  int wid = threadIdx.x >> 6;
  if ((threadIdx.x & 63) == 0) ls[wid] = s;
  __syncthreads();
  if (threadIdx.x == 0) atomicAdd(out, ls[0] + ls[1] + ls[2] + ls[3]);
}

// ---------------- degree over dst ----------------
__global__ __launch_bounds__(256) void degree_kernel(const int* __restrict__ ei,
                                                     int* __restrict__ degi, int ne) {
  int e = blockIdx.x * blockDim.x + threadIdx.x;
  if (e < ne) atomicAdd(&degi[ei[NEDGES + e]], 1);
}

__global__ __launch_bounds__(256) void dinv_kernel(const int* __restrict__ degi,
                                                   float* __restrict__ dinv, int n) {
  int i = blockIdx.x * blockDim.x + threadIdx.x;
  if (i < n) dinv[i] = (degi[i] > 0) ? rsqrtf((float)degi[i]) : 0.f;
}

// ---------------- exclusive scan (3-kernel, N=50000) ----------------
__global__ __launch_bounds__(1024) void scan1_kernel(const int* __restrict__ cnt,
                                                     int* __restrict__ exc,
                                                     int* __restrict__ bsum, int n) {
  __shared__ int s[1024];
  int tid = threadIdx.x;
  int i = blockIdx.x * 1024 + tid;
  int v = (i < n) ? cnt[i] : 0;
  int val = v;
  s[tid] = v;
  __syncthreads();
  for (int off = 1; off < 1024; off <<= 1) {
    int t = (tid >= off) ? s[tid - off] : 0;
    __syncthreads();
    val += t;
    s[tid] = val;
    __syncthreads();
  }
  if (i < n) exc[i] = val - v;
  if (tid == 1023) bsum[blockIdx.x] = val;
}

__global__ __launch_bounds__(256) void scan2_kernel(int* __restrict__ bsum, int nb) {
  __shared__ int s[256];
  int tid = threadIdx.x;
  int v = (tid < nb) ? bsum[tid] : 0;
  int val = v;
  s[tid] = v;
  __syncthreads();
  for (int off = 1; off < 256; off <<= 1) {
    int t = (tid >= off) ? s[tid - off] : 0;
    __syncthreads();
    val += t;
    s[tid] = val;
    __syncthreads();
  }
  if (tid < nb) bsum[tid] = val - v;
}

// row_ptr finalize + cursor copy + per-bucket cursor init
__global__ __launch_bounds__(256) void scan3_kernel(int* __restrict__ row_ptr,
                                                    const int* __restrict__ bsum,
                                                    int* __restrict__ cursor,
                                                    int* __restrict__ gcur, int n) {
  int i = blockIdx.x * blockDim.x + threadIdx.x;
  if (i < n) {
    int v = row_ptr[i] + bsum[i >> 10];
    row_ptr[i] = v;
    cursor[i] = v;
    if ((i & 511) == 0) gcur[i >> 9] = v;
  } else if (i == n) {
    row_ptr[n] = NEDGES;
  }
}

// ---------------- CSR build phase A: block-local counting sort into bucket runs
// Each block: 4096 edges -> LDS bucket-sort -> coalesced run writes to gstage.
// gstage layout: bucket-major (base = row_ptr[bucket*512]), unordered within bucket.
__global__ __launch_bounds__(256) void binA_kernel(const int* __restrict__ ei,
                                                   int* __restrict__ gcur,
                                                   unsigned int* __restrict__ gstage,
                                                   int ne) {
  __shared__ int hist[NBUCK];
  __shared__ int prefix[NBUCK + 1];
  __shared__ int offs[NBUCK];
  __shared__ int gbase[NBUCK];
  __shared__ unsigned int stag[4096];
  const int tid = threadIdx.x;
  const int c0 = blockIdx.x * 4096;
  for (int b = tid; b < NBUCK; b += 256) hist[b] = 0;
  __syncthreads();
  for (int i = tid; i < 4096; i += 256) {
    int e = c0 + i;
    if (e < ne) atomicAdd(&hist[ei[NEDGES + e] >> 9], 1);
  }
  __syncthreads();
  if (tid == 0) {
    int s = 0;
    for (int b = 0; b < NBUCK; ++b) { prefix[b] = s; s += hist[b]; }
    prefix[NBUCK] = s;
  }
  __syncthreads();
  if (tid < NBUCK) {
    offs[tid] = prefix[tid];
    gbase[tid] = atomicAdd(&gcur[tid], hist[tid]);
  }
  __syncthreads();
  for (int i = tid; i < 4096; i += 256) {
    int e = c0 + i;
    if (e < ne) {
      int s = ei[e];
      int d = ei[NEDGES + e];
      int b = d >> 9;
      int p = atomicAdd(&offs[b], 1);
      stag[p] = (unsigned int)s | ((unsigned int)(d & 511) << 16);
    }
  }
  __syncthreads();
  const int total = prefix[NBUCK];
  for (int j = tid; j < total; j += 256) {
    int lo = 0, hi = NBUCK;               // find bucket: prefix[lo] <= j < prefix[lo+1]
    while (hi - lo > 1) {
      int mid = (lo + hi) >> 1;
      if (prefix[mid] <= j) lo = mid; else hi = mid;
    }
    gstage[gbase[lo] + (j - prefix[lo])] = stag[j];
  }
}

// ---------------- CSR build phase B: within-bucket scatter (one block/bucket)
// All writes for a bucket land in a ~200KB window from ONE block -> L2-local.
__global__ __launch_bounds__(1024) void binB_kernel(const unsigned int* __restrict__ gstage,
                                                    const int* __restrict__ row_ptr,
                                                    const float* __restrict__ dinv,
                                                    int* __restrict__ cursor,
                                                    int2* __restrict__ ep, int n) {
  const int b = blockIdx.x;
  const int node0 = b << 9;
  const int node1 = min(n, node0 + 512);
  const int start = row_ptr[node0];
  const int end = row_ptr[node1];
  for (int i = start + threadIdx.x; i < end; i += 1024) {
    unsigned int v = gstage[i];
    int s = (int)(v & 0xFFFFu);
    int d = node0 + (int)(v >> 16);
    float w = dinv[s] * dinv[d];
    int pos = atomicAdd(&cursor[d], 1);
    ep[pos] = make_int2(s, __float_as_int(w));
  }
}

// ---------------- CSR SpMM, fp16 gathered rows, 1 node/wave edge-parallel ----
template <int F, bool ADD, bool STATS, bool BNIN, bool OUTH>
__global__ __launch_bounds__(256) void spmm_kernel(
    const int* __restrict__ row_ptr, const int2* __restrict__ ep,
    const _Float16* __restrict__ gsrc, const float* __restrict__ addL,
    const float* __restrict__ bias,
    const float* __restrict__ stats_in, const float* __restrict__ gin,
    const float* __restrict__ bein, float* __restrict__ stats_out,
    void* __restrict__ outv, int n) {
  constexpr int LPE = F / 8;     // lanes per edge
  constexpr int EPC = 64 / LPE;  // edges per chunk
  constexpr int LG  = (LPE == 2) ? 1 : 3;
  __shared__ float sst[STATS ? 2 * F : 1];
  const int tid = threadIdx.x;
  if (STATS) {
    if (tid < 2 * F) sst[tid] = 0.f;
    __syncthreads();
  }
  const int lane = tid & 63;
  const int wv = tid >> 6;
  const int sub = lane & (LPE - 1);
  const int g = lane >> LG;
  const int f0 = sub * 8;
  float scl[8], sht[8];
  if (BNIN) {
    const float inv_n = 1.0f / (float)n;
#pragma unroll
    for (int j = 0; j < 8; ++j) {
      int f = f0 + j;
      float mu = stats_in[f] * inv_n;
      float var = stats_in[F + f] * inv_n - mu * mu;
      float s = gin[f] * rsqrtf(var + EPSV);
      scl[j] = s;
      sht[j] = bein[f] - mu * s;
    }
  }
  for (int node = blockIdx.x * 4 + wv; node < n; node += gridDim.x * 4) {
    float acc[8] = {};
    const int beg = row_ptr[node], end = row_ptr[node + 1];
    int e = beg + g;
    while (e < end) {
      int2 s0 = ep[e];
      bool p1 = (e + EPC) < end;
      int2 s1 = ep[p1 ? e + EPC : e];
      float w0 = __int_as_float(s0.y);
      float w1 = p1 ? __int_as_float(s1.y) : 0.f;
      h8 r0 = *(const h8*)(gsrc + (size_t)s0.x * F + f0);
      h8 r1 = *(const h8*)(gsrc + (size_t)s1.x * F + f0);
#pragma unroll
      for (int j = 0; j < 8; ++j) {
        float v0 = (float)r0[j], v1 = (float)r1[j];
        if (BNIN) {
          v0 = fmaxf(fmaf(v0, scl[j], sht[j]), 0.f);
          v1 = fmaxf(fmaf(v1, scl[j], sht[j]), 0.f);
        }
        acc[j] = fmaf(w0, v0, acc[j]);
        acc[j] = fmaf(w1, v1, acc[j]);
      }
      e += 2 * EPC;
    }
#pragma unroll
    for (int m = LPE; m < 64; m <<= 1) {
#pragma unroll
      for (int j = 0; j < 8; ++j) acc[j] += __shfl_xor(acc[j], m);
    }
    if (lane < LPE) {
      float o[8];
      if (ADD) {
        float4 a0 = *(const float4*)&addL[(size_t)node * F + f0];
        float4 a1 = *(const float4*)&addL[(size_t)node * F + f0 + 4];
        float4 b0 = *(const float4*)&bias[f0];
        float4 b1 = *(const float4*)&bias[f0 + 4];
        o[0] = a0.x + b0.x - acc[0]; o[1] = a0.y + b0.y - acc[1];
        o[2] = a0.z + b0.z - acc[2]; o[3] = a0.w + b0.w - acc[3];
        o[4] = a1.x + b1.x - acc[4]; o[5] = a1.y + b1.y - acc[5];
        o[6] = a1.z + b1.z - acc[6]; o[7] = a1.w + b1.w - acc[7];
      } else {
#pragma unroll
        for (int j = 0; j < 8; ++j) o[j] = -acc[j];
      }
      if (OUTH) {
        h8 ho;
#pragma unroll
        for (int j = 0; j < 8; ++j) ho[j] = (_Float16)o[j];
        *(h8*)((_Float16*)outv + (size_t)node * F + f0) = ho;
      } else {
        float* op = (float*)outv + (size_t)node * F + f0;
        *(float4*)op = make_float4(o[0], o[1], o[2], o[3]);
        *(float4*)(op + 4) = make_float4(o[4], o[5], o[6], o[7]);
      }
      if (STATS) {
#pragma unroll
        for (int j = 0; j < 8; ++j) {
          atomicAdd(&sst[f0 + j], o[j]);
          atomicAdd(&sst[F + f0 + j], o[j] * o[j]);
        }
      }
    }
  }
  if (STATS) {
    __syncthreads();
    if (tid < 2 * F) atomicAdd(&stats_out[tid], sst[tid]);
  }
}

// ---------------- dense GEMM column-block ----------------
template <int K, int NB, bool ROWCAT, bool BIAS, bool BNIN, bool STATS, bool NOISE,
          bool A1H, int OMODE>
__global__ __launch_bounds__(256) void gemm_kernel(
    const void* __restrict__ A1, const float* __restrict__ A2,
    const float* __restrict__ W0, const float* __restrict__ W1,
    const float* __restrict__ bias, int col0, int wnt, int ostride, int ocol0,
    const float* __restrict__ noise, const float* __restrict__ sumv,
    const float* __restrict__ stats_in, const float* __restrict__ gin,
    const float* __restrict__ bein, float* __restrict__ stats_out,
    void* __restrict__ outv, void* __restrict__ out2, int n) {
  constexpr int TC  = NB / 4;
  constexpr int RG  = 256 / TC;
  constexpr int RPT = 4;
  constexpr int RPB = RG * RPT;
  constexpr int AP  = K + 4;
  constexpr int KB  = ROWCAT ? K / 2 : K;
  __shared__ float wl[K * NB];
  __shared__ float al[RPB * AP];
  __shared__ float sarr[BNIN ? KB : 1];
  __shared__ float tarr[BNIN ? KB : 1];
  __shared__ float sst[STATS ? 2 * NB : 1];
  const int tid = threadIdx.x;
  if (STATS && tid < 2 * NB) sst[tid] = 0.f;
  if (BNIN) {
    const float inv_n = 1.0f / (float)n;
    for (int f = tid; f < KB; f += 256) {
      float mu = stats_in[f] * inv_n;
      float var = stats_in[KB + f] * inv_n - mu * mu;
      float s = gin[f] * rsqrtf(var + EPSV);
      sarr[f] = s;
      tarr[f] = bein[f] - mu * s;
    }
  }
  float mean = 0.f;
  if (NOISE) mean = sumv[0] * (1.0f / (float)(NNODES * FEAT));

  for (int i = tid; i < K * NB; i += 256) {
    int k = i / NB, j = i - k * NB;
    int jg = col0 + j;
    float v;
    if (ROWCAT) v = (k < K / 2) ? W0[k * wnt + jg] : W1[(k - K / 2) * wnt + jg];
    else        v = (jg < wnt / 2) ? W0[k * (wnt / 2) + jg] : W1[k * (wnt / 2) + (jg - wnt / 2)];
    wl[i] = v;
  }
  __syncthreads();  // sarr/tarr ready before A staging uses them

  const int row0 = blockIdx.x * RPB;
  for (int i = tid; i < RPB * K; i += 256) {
    int r = i / K, k = i - r * K;
    int gr = row0 + r;
    float v = 0.f;
    if (gr < n) {
      if (ROWCAT) {
        if (k < K / 2) {
          v = A1H ? (float)((const _Float16*)A1)[(size_t)gr * (K / 2) + k]
                  : ((const float*)A1)[(size_t)gr * (K / 2) + k];
          if (BNIN) v = fmaxf(fmaf(v, sarr[k], tarr[k]), 0.f);
        } else {
          v = A2[(size_t)gr * (K / 2) + (k - K / 2)];
        }
      } else {
        v = A1H ? (float)((const _Float16*)A1)[(size_t)gr * K + k]
                : ((const float*)A1)[(size_t)gr * K + k];
        if (BNIN) v = fmaxf(fmaf(v, sarr[k], tarr[k]), 0.f);
        if (NOISE) v = fmaf(noise[(size_t)gr * K + k], mean, v);
      }
    }
    al[r * AP + k] = v;
  }
  __syncthreads();

  const int jt = (tid % TC) * 4;
  const int rbase = (tid / TC) * RPT;
  float4 acc[RPT];
#pragma unroll
  for (int rr = 0; rr < RPT; ++rr) acc[rr] = make_float4(0.f, 0.f, 0.f, 0.f);
  const float4* wl4 = (const float4*)wl;
  const int jt4 = jt >> 2;
#pragma unroll 4
  for (int k0 = 0; k0 < K; k0 += 4) {
    float4 w0 = wl4[(k0 + 0) * TC + jt4];
    float4 w1 = wl4[(k0 + 1) * TC + jt4];
    float4 w2 = wl4[(k0 + 2) * TC + jt4];
    float4 w3 = wl4[(k0 + 3) * TC + jt4];
#pragma unroll
    for (int rr = 0; rr < RPT; ++rr) {
      float4 a = *(const float4*)&al[(rbase + rr) * AP + k0];
      acc[rr] = f4fma(a.x, w0, acc[rr]);
      acc[rr] = f4fma(a.y, w1, acc[rr]);
      acc[rr] = f4fma(a.z, w2, acc[rr]);
      acc[rr] = f4fma(a.w, w3, acc[rr]);
    }
  }
  float4 b4 = make_float4(0.f, 0.f, 0.f, 0.f);
  if (BIAS) b4 = *(const float4*)&bias[col0 + jt];
  float sl[4] = {}, ql[4] = {};
#pragma unroll
  for (int rr = 0; rr < RPT; ++rr) {
    int gr = row0 + rbase + rr;
    if (gr < n) {
      float4 o;
      o.x = acc[rr].x + b4.x; o.y = acc[rr].y + b4.y;
      o.z = acc[rr].z + b4.z; o.w = acc[rr].w + b4.w;
      if (OMODE == 0) {
        *(float4*)((float*)outv + (size_t)gr * ostride + ocol0 + jt) = o;
      } else if (OMODE == 1) {
        h4 ho; ho[0] = (_Float16)o.x; ho[1] = (_Float16)o.y;
        ho[2] = (_Float16)o.z; ho[3] = (_Float16)o.w;
        *(h4*)((_Float16*)outv + (size_t)gr * ostride + ocol0 + jt) = ho;
      } else {
        if (jt < 16) {
          *(float4*)((float*)outv + (size_t)gr * 16 + jt) = o;
        } else {
          h4 ho; ho[0] = (_Float16)o.x; ho[1] = (_Float16)o.y;
          ho[2] = (_Float16)o.z; ho[3] = (_Float16)o.w;
          *(h4*)((_Float16*)out2 + (size_t)gr * 16 + (jt - 16)) = ho;
        }
      }
      if (STATS) {
        sl[0] += o.x; ql[0] += o.x * o.x; sl[1] += o.y; ql[1] += o.y * o.y;
        sl[2] += o.z; ql[2] += o.z * o.z; sl[3] += o.w; ql[3] += o.w * o.w;
      }
    }
  }
  if (STATS) {
#pragma unroll
    for (int j = 0; j < 4; ++j) {
      atomicAdd(&sst[jt + j], sl[j]);
      atomicAdd(&sst[NB + jt + j], ql[j]);
    }
    __syncthreads();
    if (tid < 2 * NB) atomicAdd(&stats_out[tid], sst[tid]);
  }
}

extern "C" void kernel_launch(void* const* d_in, const int* in_sizes, int n_in,
                              void* d_out, int out_size, void* d_ws, size_t ws_size,
                              hipStream_t stream) {
  const float* x     = (const float*)d_in[0];
  const float* noise = (const float*)d_in[1];
  const int*   ei    = (const int*)d_in[2];   // int32 per harness convention
  const float* W1_0 = (const float*)d_in[3];
  const float* W1_1 = (const float*)d_in[4];
  const float* b1   = (const float*)d_in[5];
  const float* g1   = (const float*)d_in[6];
  const float* be1  = (const float*)d_in[7];
  const float* W2_0 = (const float*)d_in[8];
  const float* W2_1 = (const float*)d_in[9];
  const float* b2   = (const float*)d_in[10];
  const float* W3_0 = (const float*)d_in[11];
  const float* W3_1 = (const float*)d_in[12];
  const float* b3   = (const float*)d_in[13];
  const float* g3   = (const float*)d_in[14];
  const float* be3  = (const float*)d_in[15];
  const float* W4_0 = (const float*)d_in[16];
  const float* W4_1 = (const float*)d_in[17];
  const float* b4   = (const float*)d_in[18];
  float* out = (float*)d_out;

  char* p = (char*)d_ws;
  size_t off = 0;
  auto alloc = [&](size_t b) -> void* {
    void* r = p + off;
    off += (b + 255) & ~(size_t)255;
    return r;
  };
  float* s_sum  = (float*)alloc(4);
  float* stats0 = (float*)alloc(2 * 64 * 4);
  float* stats1 = (float*)alloc(2 * 64 * 4);
  int*   degi   = (int*)alloc(sizeof(int) * NNODES);
  size_t zero_bytes = off;                       // region that must start at 0
  float*     dinv    = (float*)alloc(sizeof(float) * NNODES);
  int*       row_ptr = (int*)alloc(sizeof(int) * (NNODES + 1));
  int*       bsum    = (int*)alloc(256 * sizeof(int));
  int*       cursor  = (int*)alloc(sizeof(int) * NNODES);
  int*       gcur    = (int*)alloc(sizeof(int) * NBUCK);
  int2*      ep      = (int2*)alloc(8ULL * NEDGES);
  float*     zzL     = (float*)alloc(4ULL * NNODES * 64);   // also reused as agg4
  _Float16*  zzRh    = (_Float16*)alloc(2ULL * NNODES * 64);
  float*     h1      = (float*)alloc(4ULL * NNODES * 64);
  _Float16*  zz2Rh   = (_Float16*)alloc(2ULL * NNODES * 16);
  _Float16*  h2      = (_Float16*)alloc(2ULL * NNODES * 16);
  _Float16*  h3h     = (_Float16*)alloc(2ULL * NNODES * 64);
  float*     agg4    = zzL;  // zzL dead after spmm1

  // d_out scratch (temporally disjoint uses):
  //   gstage [0, E) uint  — CSR build only (dead after binB)
  //   zz2L   [0, N*16), agg3 [N*16, N*32) — layer2/3 only (dead before gemm4)
  unsigned int* gstage = (unsigned int*)out;
  float* zz2L = out;
  float* agg3 = out + (size_t)NNODES * 16;

  hipMemsetAsync(d_ws, 0, zero_bytes, stream);

  int n4 = NNODES * FEAT / 4;
  sum_kernel<<<2048, 256, 0, stream>>>(x, s_sum, n4);
  degree_kernel<<<(NEDGES + 255) / 256, 256, 0, stream>>>(ei, degi, NEDGES);
  dinv_kernel<<<(NNODES + 255) / 256, 256, 0, stream>>>(degi, dinv, NNODES);
  scan1_kernel<<<(NNODES + 1023) / 1024, 1024, 0, stream>>>(degi, row_ptr, bsum, NNODES);
  scan2_kernel<<<1, 256, 0, stream>>>(bsum, (NNODES + 1023) / 1024);
  scan3_kernel<<<(NNODES + 256) / 256, 256, 0, stream>>>(row_ptr, bsum, cursor, gcur, NNODES);
  binA_kernel<<<(NEDGES + 4095) / 4096, 256, 0, stream>>>(ei, gcur, gstage, NEDGES);
  binB_kernel<<<NBUCK, 1024, 0, stream>>>(gstage, row_ptr, dinv, cursor, ep, NNODES);

  // Layer 1: zzL = xn@W1_0 (f32), zzRh = fp16(xn@W1_1); h1 + stats0 via spmm
  gemm_kernel<128, 64, false, false, false, false, true, false, 0>
      <<<(NNODES + 63) / 64, 256, 0, stream>>>(
      x, nullptr, W1_0, W1_1, nullptr, 0, 128, 64, 0,
      noise, s_sum, nullptr, nullptr, nullptr, nullptr, zzL, nullptr, NNODES);
  gemm_kernel<128, 64, false, false, false, false, true, false, 1>
      <<<(NNODES + 63) / 64, 256, 0, stream>>>(
      x, nullptr, W1_0, W1_1, nullptr, 64, 128, 64, 0,
      noise, s_sum, nullptr, nullptr, nullptr, nullptr, zzRh, nullptr, NNODES);
  spmm_kernel<64, true, true, false, false><<<2048, 256, 0, stream>>>(
      row_ptr, ep, zzRh, zzL, b1, nullptr, nullptr, nullptr, stats0, h1, NNODES);

  // Layer 2: zz2L/zz2Rh = bn1(h1)@W2_{0,1} (split f32/f16); h2 (fp16) via spmm
  gemm_kernel<64, 32, false, false, true, false, false, false, 2>
      <<<(NNODES + 127) / 128, 256, 0, stream>>>(
      h1, nullptr, W2_0, W2_1, nullptr, 0, 32, 16, 0,
      nullptr, nullptr, stats0, g1, be1, nullptr, zz2L, zz2Rh, NNODES);
  spmm_kernel<16, true, false, false, true><<<2048, 256, 0, stream>>>(
      row_ptr, ep, zz2Rh, zz2L, b2, nullptr, nullptr, nullptr, nullptr, h2, NNODES);

  // Layer 3: agg3 = -A h2 (f32); h3h = fp16(h2@W3_0 + agg3@W3_1 + b3), stats1
  spmm_kernel<16, false, false, false, false><<<2048, 256, 0, stream>>>(
      row_ptr, ep, h2, nullptr, nullptr, nullptr, nullptr, nullptr, nullptr, agg3, NNODES);
  gemm_kernel<32, 64, true, true, false, true, false, true, 1>
      <<<(NNODES + 63) / 64, 256, 0, stream>>>(
      h2, agg3, W3_0, W3_1, b3, 0, 64, 64, 0,
      nullptr, nullptr, nullptr, nullptr, nullptr, stats1, h3h, nullptr, NNODES);

  // Layer 4: agg4 = -A bn3(h3h) (f32); out = bn3(h3h)@W4_0 + agg4@W4_1 + b4
  spmm_kernel<64, false, false, true, false><<<2048, 256, 0, stream>>>(
      row_ptr, ep, h3h, nullptr, nullptr, stats1, g3, be3, nullptr, agg4, NNODES);
  gemm_kernel<128, 64, true, true, true, false, false, true, 0>
      <<<(NNODES + 63) / 64, 256, 0, stream>>>(
      h3h, agg4, W4_0, W4_1, b4, 0, 128, 128, 0,
      nullptr, nullptr, stats1, g3, be3, nullptr, out, nullptr, NNODES);
  gemm_kernel<128, 64, true, true, true, false, false, true, 0>
      <<<(NNODES + 63) / 64, 256, 0, stream>>>(
      h3h, agg4, W4_0, W4_1, b4, 64, 128, 128, 64,
      nullptr, nullptr, stats1, g3, be3, nullptr, out, nullptr, NNODES);
}

// Round 13
// 685.429 us; speedup vs baseline: 1.0045x; 1.0045x over previous
//
#include <hip/hip_runtime.h>

#define NNODES 50000
#define NEDGES 1600000
#define FEAT   128
#define EPSV   1e-5f
#define NBUCK  ((NNODES + 511) / 512)   // 98 buckets of 512 nodes

typedef _Float16 h8 __attribute__((ext_vector_type(8)));
typedef _Float16 h4 __attribute__((ext_vector_type(4)));

__device__ __forceinline__ float4 f4fma(float s, float4 w, float4 a) {
  a.x = fmaf(s, w.x, a.x); a.y = fmaf(s, w.y, a.y);
  a.z = fmaf(s, w.z, a.z); a.w = fmaf(s, w.w, a.w);
  return a;
}

// ---------------- sum of all x (for mean) ----------------
__global__ __launch_bounds__(256) void sum_kernel(const float* __restrict__ x,
                                                  float* __restrict__ out, int n4) {
  const float4* x4 = (const float4*)x;
  float s = 0.f;
  for (int i = blockIdx.x * blockDim.x + threadIdx.x; i < n4; i += gridDim.x * blockDim.x) {
    float4 v = x4[i];
    s += v.x + v.y + v.z + v.w;
  }
  for (int off = 32; off > 0; off >>= 1) s += __shfl_down(s, off);
  __shared__ float ls[4];
  int wid = threadIdx.x >> 6;
  if ((threadIdx.x & 63) == 0) ls[wid] = s;
  __syncthreads();
  if (threadIdx.x == 0) atomicAdd(out, ls[0] + ls[1] + ls[2] + ls[3]);
}

// ---------------- degree over dst ----------------
__global__ __launch_bounds__(256) void degree_kernel(const int* __restrict__ ei,
                                                     int* __restrict__ degi, int ne) {
  int e = blockIdx.x * blockDim.x + threadIdx.x;
  if (e < ne) atomicAdd(&degi[ei[NEDGES + e]], 1);
}

__global__ __launch_bounds__(256) void dinv_kernel(const int* __restrict__ degi,
                                                   float* __restrict__ dinv, int n) {
  int i = blockIdx.x * blockDim.x + threadIdx.x;
  if (i < n) dinv[i] = (degi[i] > 0) ? rsqrtf((float)degi[i]) : 0.f;
}

// ---------------- exclusive scan (3-kernel, N=50000) ----------------
__global__ __launch_bounds__(1024) void scan1_kernel(const int* __restrict__ cnt,
                                                     int* __restrict__ exc,
                                                     int* __restrict__ bsum, int n) {
  __shared__ int s[1024];
  int tid = threadIdx.x;
  int i = blockIdx.x * 1024 + tid;
  int v = (i < n) ? cnt[i] : 0;
  int val = v;
  s[tid] = v;
  __syncthreads();
  for (int off = 1; off < 1024; off <<= 1) {
    int t = (tid >= off) ? s[tid - off] : 0;
    __syncthreads();
    val += t;
    s[tid] = val;
    __syncthreads();
  }
  if (i < n) exc[i] = val - v;
  if (tid == 1023) bsum[blockIdx.x] = val;
}

__global__ __launch_bounds__(256) void scan2_kernel(int* __restrict__ bsum, int nb) {
  __shared__ int s[256];
  int tid = threadIdx.x;
  int v = (tid < nb) ? bsum[tid] : 0;
  int val = v;
  s[tid] = v;
  __syncthreads();
  for (int off = 1; off < 256; off <<= 1) {
    int t = (tid >= off) ? s[tid - off] : 0;
    __syncthreads();
    val += t;
    s[tid] = val;
    __syncthreads();
  }
  if (tid < nb) bsum[tid] = val - v;
}

// row_ptr finalize + cursor copy + per-bucket cursor init
__global__ __launch_bounds__(256) void scan3_kernel(int* __restrict__ row_ptr,
                                                    const int* __restrict__ bsum,
                                                    int* __restrict__ cursor,
                                                    int* __restrict__ gcur, int n) {
  int i = blockIdx.x * blockDim.x + threadIdx.x;
  if (i < n) {
    int v = row_ptr[i] + bsum[i >> 10];
    row_ptr[i] = v;
    cursor[i] = v;
    if ((i & 511) == 0) gcur[i >> 9] = v;
  } else if (i == n) {
    row_ptr[n] = NEDGES;
  }
}

// ---------------- CSR build phase A: block-local counting sort into bucket runs
__global__ __launch_bounds__(256) void binA_kernel(const int* __restrict__ ei,
                                                   int* __restrict__ gcur,
                                                   unsigned int* __restrict__ gstage,
                                                   int ne) {
  __shared__ int hist[NBUCK];
  __shared__ int prefix[NBUCK + 1];
  __shared__ int offs[NBUCK];
  __shared__ int gbase[NBUCK];
  __shared__ unsigned int stag[4096];
  const int tid = threadIdx.x;
  const int c0 = blockIdx.x * 4096;
  for (int b = tid; b < NBUCK; b += 256) hist[b] = 0;
  __syncthreads();
  for (int i = tid; i < 4096; i += 256) {
    int e = c0 + i;
    if (e < ne) atomicAdd(&hist[ei[NEDGES + e] >> 9], 1);
  }
  __syncthreads();
  if (tid == 0) {
    int s = 0;
    for (int b = 0; b < NBUCK; ++b) { prefix[b] = s; s += hist[b]; }
    prefix[NBUCK] = s;
  }
  __syncthreads();
  if (tid < NBUCK) {
    offs[tid] = prefix[tid];
    gbase[tid] = atomicAdd(&gcur[tid], hist[tid]);
  }
  __syncthreads();
  for (int i = tid; i < 4096; i += 256) {
    int e = c0 + i;
    if (e < ne) {
      int s = ei[e];
      int d = ei[NEDGES + e];
      int b = d >> 9;
      int p = atomicAdd(&offs[b], 1);
      stag[p] = (unsigned int)s | ((unsigned int)(d & 511) << 16);
    }
  }
  __syncthreads();
  const int total = prefix[NBUCK];
  for (int j = tid; j < total; j += 256) {
    int lo = 0, hi = NBUCK;
    while (hi - lo > 1) {
      int mid = (lo + hi) >> 1;
      if (prefix[mid] <= j) lo = mid; else hi = mid;
    }
    gstage[gbase[lo] + (j - prefix[lo])] = stag[j];
  }
}

// ---------------- CSR build phase B: within-bucket scatter, u16 src only ----
__global__ __launch_bounds__(1024) void binB_kernel(const unsigned int* __restrict__ gstage,
                                                    const int* __restrict__ row_ptr,
                                                    int* __restrict__ cursor,
                                                    unsigned short* __restrict__ ep, int n) {
  const int b = blockIdx.x;
  const int node0 = b << 9;
  const int node1 = min(n, node0 + 512);
  const int start = row_ptr[node0];
  const int end = row_ptr[node1];
  for (int i = start + threadIdx.x; i < end; i += 1024) {
    unsigned int v = gstage[i];
    int s = (int)(v & 0xFFFFu);
    int d = node0 + (int)(v >> 16);
    int pos = atomicAdd(&cursor[d], 1);
    ep[pos] = (unsigned short)s;
  }
}

// ---------------- CSR SpMM, u16 edges, pre-scaled fp16 rows ----------------
// acc = sum_e scale_e * g(gsrc[src]); scale_e = GDINV ? dinv[src] : 1 (rows
// pre-scaled by producer otherwise).  o = (ADD ? addL + bias : 0) - dinv[node]*acc
// outv (fp16) = o; DUAL: out2 (fp16) = dinv[node]*o (pre-scaled copy for next gather).
template <int F, bool ADD, bool ADDH, bool STATS, bool BNIN, bool GDINV, bool DUAL>
__global__ __launch_bounds__(256) void spmm_kernel(
    const int* __restrict__ row_ptr, const unsigned short* __restrict__ ep,
    const _Float16* __restrict__ gsrc, const void* __restrict__ addL,
    const float* __restrict__ bias, const float* __restrict__ dinv,
    const float* __restrict__ stats_in, const float* __restrict__ gin,
    const float* __restrict__ bein, float* __restrict__ stats_out,
    _Float16* __restrict__ outv, _Float16* __restrict__ out2, int n) {
  constexpr int LPE = F / 8;     // lanes per edge
  constexpr int EPC = 64 / LPE;  // edges per chunk
  constexpr int LG  = (LPE == 2) ? 1 : 3;
  __shared__ float sst[STATS ? 2 * F : 1];
  const int tid = threadIdx.x;
  if (STATS) {
    if (tid < 2 * F) sst[tid] = 0.f;
    __syncthreads();
  }
  const int lane = tid & 63;
  const int wv = tid >> 6;
  const int sub = lane & (LPE - 1);
  const int g = lane >> LG;
  const int f0 = sub * 8;
  float scl[8], sht[8];
  if (BNIN) {
    const float inv_n = 1.0f / (float)n;
#pragma unroll
    for (int j = 0; j < 8; ++j) {
      int f = f0 + j;
      float mu = stats_in[f] * inv_n;
      float var = stats_in[F + f] * inv_n - mu * mu;
      float s = gin[f] * rsqrtf(var + EPSV);
      scl[j] = s;
      sht[j] = bein[f] - mu * s;
    }
  }
  for (int node = blockIdx.x * 4 + wv; node < n; node += gridDim.x * 4) {
    float acc[8] = {};
    const int beg = row_ptr[node], end = row_ptr[node + 1];
    int e = beg + g;
    while (e < end) {
      int s0 = ep[e];
      bool p1 = (e + EPC) < end;
      int s1 = ep[p1 ? e + EPC : e];
      float dv0 = 0.f, dv1 = 0.f;
      if (GDINV) {
        dv0 = dinv[s0];
        dv1 = p1 ? dinv[s1] : 0.f;
      }
      h8 r0 = *(const h8*)(gsrc + (size_t)s0 * F + f0);
      h8 r1 = *(const h8*)(gsrc + (size_t)s1 * F + f0);
#pragma unroll
      for (int j = 0; j < 8; ++j) {
        float v0 = (float)r0[j], v1 = (float)r1[j];
        if (BNIN) {
          v0 = fmaxf(fmaf(v0, scl[j], sht[j]), 0.f);
          v1 = fmaxf(fmaf(v1, scl[j], sht[j]), 0.f);
        }
        if (GDINV) {
          acc[j] = fmaf(dv0, v0, acc[j]);
          acc[j] = fmaf(dv1, v1, acc[j]);
        } else {
          acc[j] += v0;
          acc[j] += p1 ? v1 : 0.f;
        }
      }
      e += 2 * EPC;
    }
#pragma unroll
    for (int m = LPE; m < 64; m <<= 1) {
#pragma unroll
      for (int j = 0; j < 8; ++j) acc[j] += __shfl_xor(acc[j], m);
    }
    if (lane < LPE) {
      const float dn = dinv[node];
      float o[8];
#pragma unroll
      for (int j = 0; j < 8; ++j) {
        float base = 0.f;
        if (ADD) {
          float a = ADDH ? (float)((const _Float16*)addL)[(size_t)node * F + f0 + j]
                         : ((const float*)addL)[(size_t)node * F + f0 + j];
          base = a + bias[f0 + j];
        }
        o[j] = base - dn * acc[j];
      }
      h8 ho;
#pragma unroll
      for (int j = 0; j < 8; ++j) ho[j] = (_Float16)o[j];
      *(h8*)(outv + (size_t)node * F + f0) = ho;
      if (DUAL) {
        h8 hs;
#pragma unroll
        for (int j = 0; j < 8; ++j) hs[j] = (_Float16)(dn * o[j]);
        *(h8*)(out2 + (size_t)node * F + f0) = hs;
      }
      if (STATS) {
#pragma unroll
        for (int j = 0; j < 8; ++j) {
          atomicAdd(&sst[f0 + j], o[j]);
          atomicAdd(&sst[F + f0 + j], o[j] * o[j]);
        }
      }
    }
  }
  if (STATS) {
    __syncthreads();
    if (tid < 2 * F) atomicAdd(&stats_out[tid], sst[tid]);
  }
}

// ---------------- dense GEMM column-block ----------------
// A1H/A2H: inputs fp16. RSCL: multiply output row by rowscl[gr] before fp16
// store (OMODE 1) or on the fp16 half only (OMODE 2). OMODE 0: f32 out.
template <int K, int NB, bool ROWCAT, bool BIAS, bool BNIN, bool STATS, bool NOISE,
          bool A1H, bool A2H, bool RSCL, int OMODE>
__global__ __launch_bounds__(256) void gemm_kernel(
    const void* __restrict__ A1, const void* __restrict__ A2,
    const float* __restrict__ W0, const float* __restrict__ W1,
    const float* __restrict__ bias, int col0, int wnt, int ostride, int ocol0,
    const float* __restrict__ noise, const float* __restrict__ sumv,
    const float* __restrict__ stats_in, const float* __restrict__ gin,
    const float* __restrict__ bein, float* __restrict__ stats_out,
    const float* __restrict__ rowscl,
    void* __restrict__ outv, void* __restrict__ out2, int n) {
  constexpr int TC  = NB / 4;
  constexpr int RG  = 256 / TC;
  constexpr int RPT = 4;
  constexpr int RPB = RG * RPT;
  constexpr int AP  = K + 4;
  constexpr int KB  = ROWCAT ? K / 2 : K;
  __shared__ float wl[K * NB];
  __shared__ float al[RPB * AP];
  __shared__ float sarr[BNIN ? KB : 1];
  __shared__ float tarr[BNIN ? KB : 1];
  __shared__ float sst[STATS ? 2 * NB : 1];
  const int tid = threadIdx.x;
  if (STATS && tid < 2 * NB) sst[tid] = 0.f;
  if (BNIN) {
    const float inv_n = 1.0f / (float)n;
    for (int f = tid; f < KB; f += 256) {
      float mu = stats_in[f] * inv_n;
      float var = stats_in[KB + f] * inv_n - mu * mu;
      float s = gin[f] * rsqrtf(var + EPSV);
      sarr[f] = s;
      tarr[f] = bein[f] - mu * s;
    }
  }
  float mean = 0.f;
  if (NOISE) mean = sumv[0] * (1.0f / (float)(NNODES * FEAT));

  for (int i = tid; i < K * NB; i += 256) {
    int k = i / NB, j = i - k * NB;
    int jg = col0 + j;
    float v;
    if (ROWCAT) v = (k < K / 2) ? W0[k * wnt + jg] : W1[(k - K / 2) * wnt + jg];
    else        v = (jg < wnt / 2) ? W0[k * (wnt / 2) + jg] : W1[k * (wnt / 2) + (jg - wnt / 2)];
    wl[i] = v;
  }
  __syncthreads();  // sarr/tarr ready before A staging uses them

  const int row0 = blockIdx.x * RPB;
  for (int i = tid; i < RPB * K; i += 256) {
    int r = i / K, k = i - r * K;
    int gr = row0 + r;
    float v = 0.f;
    if (gr < n) {
      if (ROWCAT) {
        if (k < K / 2) {
          v = A1H ? (float)((const _Float16*)A1)[(size_t)gr * (K / 2) + k]
                  : ((const float*)A1)[(size_t)gr * (K / 2) + k];
          if (BNIN) v = fmaxf(fmaf(v, sarr[k], tarr[k]), 0.f);
        } else {
          v = A2H ? (float)((const _Float16*)A2)[(size_t)gr * (K / 2) + (k - K / 2)]
                  : ((const float*)A2)[(size_t)gr * (K / 2) + (k - K / 2)];
        }
      } else {
        v = A1H ? (float)((const _Float16*)A1)[(size_t)gr * K + k]
                : ((const float*)A1)[(size_t)gr * K + k];
        if (BNIN) v = fmaxf(fmaf(v, sarr[k], tarr[k]), 0.f);
        if (NOISE) v = fmaf(noise[(size_t)gr * K + k], mean, v);
      }
    }
    al[r * AP + k] = v;
  }
  __syncthreads();

  const int jt = (tid % TC) * 4;
  const int rbase = (tid / TC) * RPT;
  float4 acc[RPT];
#pragma unroll
  for (int rr = 0; rr < RPT; ++rr) acc[rr] = make_float4(0.f, 0.f, 0.f, 0.f);
  const float4* wl4 = (const float4*)wl;
  const int jt4 = jt >> 2;
#pragma unroll 4
  for (int k0 = 0; k0 < K; k0 += 4) {
    float4 w0 = wl4[(k0 + 0) * TC + jt4];
    float4 w1 = wl4[(k0 + 1) * TC + jt4];
    float4 w2 = wl4[(k0 + 2) * TC + jt4];
    float4 w3 = wl4[(k0 + 3) * TC + jt4];
#pragma unroll
    for (int rr = 0; rr < RPT; ++rr) {
      float4 a = *(const float4*)&al[(rbase + rr) * AP + k0];
      acc[rr] = f4fma(a.x, w0, acc[rr]);
      acc[rr] = f4fma(a.y, w1, acc[rr]);
      acc[rr] = f4fma(a.z, w2, acc[rr]);
      acc[rr] = f4fma(a.w, w3, acc[rr]);
    }
  }
  float4 b4 = make_float4(0.f, 0.f, 0.f, 0.f);
  if (BIAS) b4 = *(const float4*)&bias[col0 + jt];
  float sl[4] = {}, ql[4] = {};
#pragma unroll
  for (int rr = 0; rr < RPT; ++rr) {
    int gr = row0 + rbase + rr;
    if (gr < n) {
      float4 o;
      o.x = acc[rr].x + b4.x; o.y = acc[rr].y + b4.y;
      o.z = acc[rr].z + b4.z; o.w = acc[rr].w + b4.w;
      float fac = RSCL ? rowscl[gr] : 1.f;
      if (OMODE == 0) {
        *(float4*)((float*)outv + (size_t)gr * ostride + ocol0 + jt) = o;
      } else if (OMODE == 1) {
        h4 ho; ho[0] = (_Float16)(o.x * fac); ho[1] = (_Float16)(o.y * fac);
        ho[2] = (_Float16)(o.z * fac); ho[3] = (_Float16)(o.w * fac);
        *(h4*)((_Float16*)outv + (size_t)gr * ostride + ocol0 + jt) = ho;
      } else {
        if (jt < 16) {
          *(float4*)((float*)outv + (size_t)gr * 16 + jt) = o;
        } else {
          h4 ho; ho[0] = (_Float16)(o.x * fac); ho[1] = (_Float16)(o.y * fac);
          ho[2] = (_Float16)(o.z * fac); ho[3] = (_Float16)(o.w * fac);
          *(h4*)((_Float16*)out2 + (size_t)gr * 16 + (jt - 16)) = ho;
        }
      }
      if (STATS) {
        sl[0] += o.x; ql[0] += o.x * o.x; sl[1] += o.y; ql[1] += o.y * o.y;
        sl[2] += o.z; ql[2] += o.z * o.z; sl[3] += o.w; ql[3] += o.w * o.w;
      }
    }
  }
  if (STATS) {
#pragma unroll
    for (int j = 0; j < 4; ++j) {
      atomicAdd(&sst[jt + j], sl[j]);
      atomicAdd(&sst[NB + jt + j], ql[j]);
    }
    __syncthreads();
    if (tid < 2 * NB) atomicAdd(&stats_out[tid], sst[tid]);
  }
}

extern "C" void kernel_launch(void* const* d_in, const int* in_sizes, int n_in,
                              void* d_out, int out_size, void* d_ws, size_t ws_size,
                              hipStream_t stream) {
  const float* x     = (const float*)d_in[0];
  const float* noise = (const float*)d_in[1];
  const int*   ei    = (const int*)d_in[2];   // int32 per harness convention
  const float* W1_0 = (const float*)d_in[3];
  const float* W1_1 = (const float*)d_in[4];
  const float* b1   = (const float*)d_in[5];
  const float* g1   = (const float*)d_in[6];
  const float* be1  = (const float*)d_in[7];
  const float* W2_0 = (const float*)d_in[8];
  const float* W2_1 = (const float*)d_in[9];
  const float* b2   = (const float*)d_in[10];
  const float* W3_0 = (const float*)d_in[11];
  const float* W3_1 = (const float*)d_in[12];
  const float* b3   = (const float*)d_in[13];
  const float* g3   = (const float*)d_in[14];
  const float* be3  = (const float*)d_in[15];
  const float* W4_0 = (const float*)d_in[16];
  const float* W4_1 = (const float*)d_in[17];
  const float* b4   = (const float*)d_in[18];
  float* out = (float*)d_out;

  char* p = (char*)d_ws;
  size_t off = 0;
  auto alloc = [&](size_t b) -> void* {
    void* r = p + off;
    off += (b + 255) & ~(size_t)255;
    return r;
  };
  float* s_sum  = (float*)alloc(4);
  float* stats0 = (float*)alloc(2 * 64 * 4);
  float* stats1 = (float*)alloc(2 * 64 * 4);
  int*   degi   = (int*)alloc(sizeof(int) * NNODES);
  size_t zero_bytes = off;                       // region that must start at 0
  float*          dinv    = (float*)alloc(sizeof(float) * NNODES);
  int*            row_ptr = (int*)alloc(sizeof(int) * (NNODES + 1));
  int*            bsum    = (int*)alloc(256 * sizeof(int));
  int*            cursor  = (int*)alloc(sizeof(int) * NNODES);
  int*            gcur    = (int*)alloc(sizeof(int) * NBUCK);
  unsigned short* ep16    = (unsigned short*)alloc(2ULL * NEDGES);
  _Float16*       zzLh    = (_Float16*)alloc(2ULL * NNODES * 64);  // reused as agg4h
  _Float16*       zzRh    = (_Float16*)alloc(2ULL * NNODES * 64);
  _Float16*       h1h     = (_Float16*)alloc(2ULL * NNODES * 64);
  _Float16*       zz2Rh   = (_Float16*)alloc(2ULL * NNODES * 16);
  _Float16*       h2h     = (_Float16*)alloc(2ULL * NNODES * 16);
  _Float16*       h2sh    = (_Float16*)alloc(2ULL * NNODES * 16);
  _Float16*       h3h     = (_Float16*)alloc(2ULL * NNODES * 64);
  _Float16*       agg4h   = zzLh;  // zzLh dead after spmm1

  // d_out scratch (temporally disjoint uses):
  //   gstage u32 [0, 4E bytes) — CSR build only (dead after binB)
  //   zz2L f32 [0, N*16 floats); agg3h fp16 at float offset N*16 — dead pre-gemm4
  unsigned int* gstage = (unsigned int*)out;
  float*    zz2L  = out;
  _Float16* agg3h = (_Float16*)(out + (size_t)NNODES * 16);

  hipMemsetAsync(d_ws, 0, zero_bytes, stream);

  int n4 = NNODES * FEAT / 4;
  sum_kernel<<<2048, 256, 0, stream>>>(x, s_sum, n4);
  degree_kernel<<<(NEDGES + 255) / 256, 256, 0, stream>>>(ei, degi, NEDGES);
  dinv_kernel<<<(NNODES + 255) / 256, 256, 0, stream>>>(degi, dinv, NNODES);
  scan1_kernel<<<(NNODES + 1023) / 1024, 1024, 0, stream>>>(degi, row_ptr, bsum, NNODES);
  scan2_kernel<<<1, 256, 0, stream>>>(bsum, (NNODES + 1023) / 1024);
  scan3_kernel<<<(NNODES + 256) / 256, 256, 0, stream>>>(row_ptr, bsum, cursor, gcur, NNODES);
  binA_kernel<<<(NEDGES + 4095) / 4096, 256, 0, stream>>>(ei, gcur, gstage, NEDGES);
  binB_kernel<<<NBUCK, 1024, 0, stream>>>(gstage, row_ptr, cursor, ep16, NNODES);

  // Layer 1: zzLh = fp16(xn@W1_0); zzRh = fp16(dinv*(xn@W1_1)); h1h + stats0
  gemm_kernel<128, 64, false, false, false, false, true, false, false, false, 1>
      <<<(NNODES + 63) / 64, 256, 0, stream>>>(
      x, nullptr, W1_0, W1_1, nullptr, 0, 128, 64, 0,
      noise, s_sum, nullptr, nullptr, nullptr, nullptr, nullptr, zzLh, nullptr, NNODES);
  gemm_kernel<128, 64, false, false, false, false, true, false, false, true, 1>
      <<<(NNODES + 63) / 64, 256, 0, stream>>>(
      x, nullptr, W1_0, W1_1, nullptr, 64, 128, 64, 0,
      noise, s_sum, nullptr, nullptr, nullptr, nullptr, dinv, zzRh, nullptr, NNODES);
  spmm_kernel<64, true, true, true, false, false, false><<<2048, 256, 0, stream>>>(
      row_ptr, ep16, zzRh, zzLh, b1, dinv, nullptr, nullptr, nullptr, stats0,
      h1h, nullptr, NNODES);

  // Layer 2: zz2L (f32) / zz2Rh (fp16, dinv-scaled) = bn1(h1)@W2_{0,1};
  //          h2h (unscaled) + h2sh (dinv-scaled) via spmm DUAL
  gemm_kernel<64, 32, false, false, true, false, false, true, false, true, 2>
      <<<(NNODES + 127) / 128, 256, 0, stream>>>(
      h1h, nullptr, W2_0, W2_1, nullptr, 0, 32, 16, 0,
      nullptr, nullptr, stats0, g1, be1, nullptr, dinv, zz2L, zz2Rh, NNODES);
  spmm_kernel<16, true, false, false, false, false, true><<<2048, 256, 0, stream>>>(
      row_ptr, ep16, zz2Rh, zz2L, b2, dinv, nullptr, nullptr, nullptr, nullptr,
      h2h, h2sh, NNODES);

  // Layer 3: agg3h = fp16(-A h2); h3h = fp16(h2@W3_0 + agg3@W3_1 + b3), stats1
  spmm_kernel<16, false, false, false, false, false, false><<<2048, 256, 0, stream>>>(
      row_ptr, ep16, h2sh, nullptr, nullptr, dinv, nullptr, nullptr, nullptr, nullptr,
      agg3h, nullptr, NNODES);
  gemm_kernel<32, 64, true, true, false, true, false, true, true, false, 1>
      <<<(NNODES + 63) / 64, 256, 0, stream>>>(
      h2h, agg3h, W3_0, W3_1, b3, 0, 64, 64, 0,
      nullptr, nullptr, nullptr, nullptr, nullptr, stats1, nullptr, h3h, nullptr, NNODES);

  // Layer 4: agg4h = fp16(-A bn3(h3)) via GDINV; out = bn3(h3)@W4_0 + agg4@W4_1 + b4
  spmm_kernel<64, false, false, false, true, true, false><<<2048, 256, 0, stream>>>(
      row_ptr, ep16, h3h, nullptr, nullptr, dinv, stats1, g3, be3, nullptr,
      agg4h, nullptr, NNODES);
  gemm_kernel<128, 64, true, true, true, false, false, true, true, false, 0>
      <<<(NNODES + 63) / 64, 256, 0, stream>>>(
      h3h, agg4h, W4_0, W4_1, b4, 0, 128, 128, 0,
      nullptr, nullptr, stats1, g3, be3, nullptr, nullptr, out, nullptr, NNODES);
  gemm_kernel<128, 64, true, true, true, false, false, true, true, false, 0>
      <<<(NNODES + 63) / 64, 256, 0, stream>>>(
      h3h, agg4h, W4_0, W4_1, b4, 64, 128, 128, 64,
      nullptr, nullptr, stats1, g3, be3, nullptr, nullptr, out, nullptr, NNODES);
}